// Round 1
// baseline (345.138 us; speedup 1.0000x reference)
//
#include <hip/hip_runtime.h>
#include <math.h>

#define N_PTS 100000
#define P_PROP 256
#define R_FEAT 256
#define NCLS 21          // C + 1
#define NSEG 32          // segments; xyz window 37.5KB + fW window 262KB << 4 MiB XCD-L2
#define SEG_LEN (N_PTS / NSEG)   // 3125 exactly
#define LIST_MAX 3136    // >= SEG_LEN, multiple of 64
#define FW_STRIDE 42     // packed bf16 channels per point row (21 cls | 21 obj)
#define ACC_STRIDE 44    // 42 channel sums + 1 count + 1 pad (16B-aligned rows)

typedef unsigned short u16t;
typedef unsigned int u32t;

__device__ __forceinline__ u16t f2bf_rne(float x) {
    u32t u = __float_as_uint(x);
    u += 0x7fffu + ((u >> 16) & 1u);
    return (u16t)(u >> 16);
}
__device__ __forceinline__ float bf2f(u16t v) {
    return __uint_as_float(((u32t)v) << 16);
}

// ---------------- Kernel 0: fW = feats @ [Wc | Wo], fp32 accum -> bf16 -----
// (sum_i feats_i) @ W == sum_i (feats_i @ W): precomputing per-point head
// projections shrinks the gather payload 256ch(1KB) -> 42ch(84B bf16).
// Thread = one point row; 42 fp32 accumulators; W read via uniform (scalar)
// loads; float4 row stream with one-ahead prefetch. Block 0 also zeroes the
// global accumulator that kernel 1 atomically adds into.
__global__ __launch_bounds__(256) void featw_kernel(
    const float* __restrict__ feats,   // (N,R)
    const float* __restrict__ Wc,      // (R,21)
    const float* __restrict__ Wo,      // (R,21)
    u16t* __restrict__ fwb,            // (N,42) bf16
    float* __restrict__ gacc)          // (P,44) fp32: 42 sums + count
{
    const int t = threadIdx.x;
    if (blockIdx.x == 0) {
        for (int i = t; i < P_PROP * ACC_STRIDE; i += 256) gacc[i] = 0.0f;
    }
    const int row = blockIdx.x * 256 + t;
    if (row >= N_PTS) return;

    float acc[2 * NCLS];
#pragma unroll
    for (int c = 0; c < 2 * NCLS; ++c) acc[c] = 0.0f;

    const float4* __restrict__ frow = (const float4*)(feats + (size_t)row * R_FEAT);
    float4 a = frow[0];
#pragma unroll 1
    for (int r4 = 0; r4 < R_FEAT / 4; ++r4) {
        const float4 anext = frow[(r4 + 1 < R_FEAT / 4) ? r4 + 1 : r4];
        const int r = r4 * 4;
#pragma unroll
        for (int k = 0; k < 4; ++k) {
            const float av = (k == 0) ? a.x : (k == 1) ? a.y : (k == 2) ? a.z : a.w;
            const float* __restrict__ wcr = Wc + (r + k) * NCLS;  // uniform -> s_load
            const float* __restrict__ wor = Wo + (r + k) * NCLS;
#pragma unroll
            for (int c = 0; c < NCLS; ++c) {
                acc[c]        = fmaf(av, wcr[c], acc[c]);
                acc[NCLS + c] = fmaf(av, wor[c], acc[NCLS + c]);
            }
        }
        a = anext;
    }

    // store 42 bf16 as 21 dwords (row byte offset 84*row is 4B-aligned)
    u32t* __restrict__ outp = (u32t*)(fwb + (size_t)row * FW_STRIDE);
#pragma unroll
    for (int j = 0; j < NCLS; ++j) {
        outp[j] = (u32t)f2bf_rne(acc[2 * j]) | ((u32t)f2bf_rne(acc[2 * j + 1]) << 16);
    }
}

// ---------------- Kernel 1: masked per-segment sums of fW, atomic combine --
// grid = 8192 blocks, XCD-swizzled: bid = q*2048 + p*8 + x, s = q*8 + x.
// Mask+compact pass identical to the proven kernel. Gather: lane c (<42)
// owns channel c; 8 rows in flight per wave; bf16 load + convert + add.
// Cross-wave LDS reduce, then 42 atomicAdds/block into gacc (32-way
// contention per address) -- this deletes the old head_logits kernel and
// its 8 MiB psums intermediate.
__global__ __launch_bounds__(256) void roi_partial_kernel(
    const float* __restrict__ proposals,   // (P,6)
    const float* __restrict__ xyz,         // (N,3)
    const u16t* __restrict__ fwb,          // (N,42) bf16
    float* __restrict__ gacc)              // (P,44)
{
    const int bid = blockIdx.x;
    const int x = bid & 7;
    const int p = (bid >> 3) & (P_PROP - 1);
    const int q = bid >> 11;
    const int s = q * 8 + x;

    const int t = threadIdx.x;
    const int wave = t >> 6;
    const int lane = t & 63;

    const float cx = proposals[p * 6 + 0];
    const float cy = proposals[p * 6 + 1];
    const float cz = proposals[p * 6 + 2];
    const float hx = proposals[p * 6 + 3] * 0.5f;
    const float hy = proposals[p * 6 + 4] * 0.5f;
    const float hz = proposals[p * 6 + 5] * 0.5f;
    const float lox = cx - hx, hix = cx + hx;
    const float loy = cy - hy, hiy = cy + hy;
    const float loz = cz - hz, hiz = cz + hz;

    __shared__ int list[LIST_MAX];
    __shared__ float red[4][48];
    __shared__ int cnt;

    if (t == 0) cnt = 0;
    __syncthreads();

    const int n0 = s * SEG_LEN;
    const int n1 = n0 + SEG_LEN;

    // ---- mask + compact (single pass over the segment) ----
    for (int i = n0 + t; i < n1; i += 256) {
        const float xx = xyz[i * 3 + 0];
        const float yy = xyz[i * 3 + 1];
        const float zz = xyz[i * 3 + 2];
        const bool in = (xx >= lox) & (xx <= hix) &
                        (yy >= loy) & (yy <= hiy) &
                        (zz >= loz) & (zz <= hiz);
        const unsigned long long b = __ballot(in);
        const int prefix = __popcll(b & ((1ull << lane) - 1ull));
        const int nb = __popcll(b);
        int baseoff = 0;
        if (lane == 0 && nb) baseoff = atomicAdd(&cnt, nb);
        baseoff = __shfl(baseoff, 0, 64);
        if (in) list[baseoff + prefix] = i;
    }
    __syncthreads();

    const int m = cnt;

    // ---- gather: lane = channel, wave-strided rows, 8 rows in flight ----
    if (lane < 2 * NCLS) {
        float acc = 0.0f;
        int j = wave;
        for (; j + 28 < m; j += 32) {
            int r[8];
#pragma unroll
            for (int u = 0; u < 8; ++u) r[u] = list[j + 4 * u];
            u16t f[8];
#pragma unroll
            for (int u = 0; u < 8; ++u)
                f[u] = fwb[(size_t)r[u] * FW_STRIDE + lane];
#pragma unroll
            for (int u = 0; u < 8; ++u) acc += bf2f(f[u]);
        }
        for (; j < m; j += 4) {
            acc += bf2f(fwb[(size_t)list[j] * FW_STRIDE + lane]);
        }
        red[wave][lane] = acc;
    }
    __syncthreads();

    if (t < 2 * NCLS) {
        const float v = red[0][t] + red[1][t] + red[2][t] + red[3][t];
        atomicAdd(&gacc[p * ACC_STRIDE + t], v);
    }
    if (t == 2 * NCLS) {
        atomicAdd(&gacc[p * ACC_STRIDE + 42], (float)m);
    }
}

// ---------------- Kernel 2: logits from gacc + softmaxes + product --------
// single block, 256 threads; thread t = proposal t. Reads its 176B gacc row,
// forms logits = sums/max(cnt,1) + bias, then the proven softmax structure:
// row softmax (cls) in registers, column softmax (obj) via 8x32 LDS groups.
__global__ __launch_bounds__(256) void softmax_mul_kernel(
    const float* __restrict__ gacc,        // (P,44)
    const float* __restrict__ bc,          // (21)
    const float* __restrict__ bo,          // (21)
    float* __restrict__ out)               // (P,21)
{
    const int t = threadIdx.x;
    const int cc = t & 31;
    const int g = t >> 5;

    __shared__ float objl[P_PROP][NCLS];
    __shared__ float red[8][32];
    __shared__ float colmax[32];
    __shared__ float colsum[32];

    float4 vv[11];
    const float4* __restrict__ rowp = (const float4*)(gacc + t * ACC_STRIDE);
#pragma unroll
    for (int j = 0; j < 11; ++j) vv[j] = rowp[j];
    const float* v = (const float*)vv;

    const float cntv = fmaxf(v[42], 1.0f);
    const float rinv = 1.0f / cntv;

    float cl[NCLS], ob[NCLS];
#pragma unroll
    for (int c = 0; c < NCLS; ++c) {
        cl[c] = v[c] * rinv + bc[c];
        ob[c] = v[NCLS + c] * rinv + bo[c];
        objl[t][c] = ob[c];
    }
    __syncthreads();

    // column max (over proposals), 8 groups of 32
    float m = -INFINITY;
    if (cc < NCLS) {
        const int p0 = g * 32;
        for (int p = p0; p < p0 + 32; ++p) m = fmaxf(m, objl[p][cc]);
    }
    red[g][cc] = m;
    __syncthreads();
    if (t < NCLS) {
        float mm = red[0][t];
#pragma unroll
        for (int gg = 1; gg < 8; ++gg) mm = fmaxf(mm, red[gg][t]);
        colmax[t] = mm;
    }
    __syncthreads();

    // column sum of exp
    float sc = 0.0f;
    if (cc < NCLS) {
        const float mm = colmax[cc];
        const int p0 = g * 32;
        for (int p = p0; p < p0 + 32; ++p) sc += expf(objl[p][cc] - mm);
    }
    red[g][cc] = sc;
    __syncthreads();
    if (t < NCLS) {
        float ss = red[0][t];
#pragma unroll
        for (int gg = 1; gg < 8; ++gg) ss += red[gg][t];
        colsum[t] = ss;
    }

    // row softmax (cls) in registers meanwhile
    float rm = cl[0];
#pragma unroll
    for (int c = 1; c < NCLS; ++c) rm = fmaxf(rm, cl[c]);
    float e[NCLS];
    float rs = 0.0f;
#pragma unroll
    for (int c = 0; c < NCLS; ++c) { e[c] = expf(cl[c] - rm); rs += e[c]; }
    const float inv = 1.0f / rs;

    __syncthreads();

#pragma unroll
    for (int c = 0; c < NCLS; ++c) {
        const float cp = e[c] * inv;
        const float op = expf(ob[c] - colmax[c]) / colsum[c];
        out[t * NCLS + c] = cp * op;
    }
}

// ---------------- launch ----------------------------------------------------
extern "C" void kernel_launch(void* const* d_in, const int* in_sizes, int n_in,
                              void* d_out, int out_size, void* d_ws, size_t ws_size,
                              hipStream_t stream) {
    const float* proposals = (const float*)d_in[0];  // (256,6)
    const float* xyz       = (const float*)d_in[1];  // (100000,3)
    const float* feats     = (const float*)d_in[2];  // (100000,256)
    const float* Wc        = (const float*)d_in[3];  // (256,21)
    const float* bc        = (const float*)d_in[4];  // (21)
    const float* Wo        = (const float*)d_in[5];  // (256,21)
    const float* bo        = (const float*)d_in[6];  // (21)
    float* out = (float*)d_out;                      // (256,21)

    char* ws = (char*)d_ws;
    u16t* fwb  = (u16t*)(ws);                        // 100000*42*2 = 8,400,000 B
    float* gacc = (float*)(ws + 8400000);            // 256*44*4    = 45,056 B

    featw_kernel<<<(N_PTS + 255) / 256, 256, 0, stream>>>(feats, Wc, Wo, fwb, gacc);
    roi_partial_kernel<<<P_PROP * NSEG, 256, 0, stream>>>(proposals, xyz, fwb, gacc);
    softmax_mul_kernel<<<1, 256, 0, stream>>>(gacc, bc, bo, out);
}

// Round 2
// 222.722 us; speedup vs baseline: 1.5496x; 1.5496x over previous
//
#include <hip/hip_runtime.h>
#include <math.h>

#define N_PTS 100000
#define P_PROP 256
#define R_FEAT 256
#define NCLS 21          // C + 1
#define NSEG 32          // segments; xyz window 37.5KB + fW window 262KB << 4 MiB XCD-L2
#define SEG_LEN (N_PTS / NSEG)   // 3125 exactly
#define LIST_MAX 3136    // >= SEG_LEN, multiple of 64
#define FW_STRIDE 42     // packed bf16 channels per point row (21 cls | 21 obj)
#define ACC_STRIDE 44    // 42 channel sums + 1 count + 1 pad (16B-aligned rows)
#define MTILE 64         // rows per featw block (4 waves x 16-row MFMA tiles)
#define FEATW_BLOCKS ((N_PTS + MTILE - 1) / MTILE)   // 1563

typedef unsigned short u16t;
typedef unsigned int u32t;
typedef __attribute__((ext_vector_type(8))) short short8;   // 8 bf16 (4 VGPRs)
typedef __attribute__((ext_vector_type(4))) float f32x4;    // MFMA accumulator

__device__ __forceinline__ u16t f2bf_rne(float x) {
    u32t u = __float_as_uint(x);
    u += 0x7fffu + ((u >> 16) & 1u);
    return (u16t)(u >> 16);
}
__device__ __forceinline__ float bf2f(u16t v) {
    return __uint_as_float(((u32t)v) << 16);
}

// ---------------- Kernel 0: fW = feats @ [Wc | Wo] via bf16 MFMA -----------
// (sum_i feats_i) @ W == sum_i (feats_i @ W). 100000x256 @ 256x48 (cols =
// 21 cls | 21 obj | 6 zero-pad) with mfma_f32_16x16x32_bf16.
// Block = 256 thr = 4 waves, each wave one 16-row M-tile, 3 N-tiles of 16.
// B (48 cols x 256 k) is bf16-converted once per block and stored in LDS
// pre-swizzled into per-(ntile,kstep,lane) 16B fragments -> one ds_read_b128
// per B-frag in the K-loop. A-frags: two float4 global loads + pack to bf16.
// Accumulators are explicit f32x4 (round-1 failure: acc[42] array -> scratch,
// VGPR=28, 175us latency-bound).
// Fragment layouts (guide-verified): A lane l: row=l&15, k=(l>>4)*8+j;
// B lane l: col=l&15, k=(l>>4)*8+j; D: col=lane&15, row=(lane>>4)*4+reg.
__global__ __launch_bounds__(256) void featw_kernel(
    const float* __restrict__ feats,   // (N,R)
    const float* __restrict__ Wc,      // (R,21)
    const float* __restrict__ Wo,      // (R,21)
    u16t* __restrict__ fwb,            // (N,42) bf16
    float* __restrict__ gacc)          // (P,44) fp32: 42 sums + count (zeroed here)
{
    const int t = threadIdx.x;
    if (blockIdx.x == 0) {
        for (int i = t; i < P_PROP * ACC_STRIDE; i += 256) gacc[i] = 0.0f;
    }

    __shared__ u16t bB[3 * 8 * 64 * 8];   // 12288 bf16 = 24 KiB of B-frags

    // ---- stage B: 1536 fragments, 6 per thread ----
    for (int idx = t; idx < 3 * 8 * 64; idx += 256) {
        const int n   = idx >> 9;         // N-tile 0..2
        const int rem = idx & 511;
        const int kk  = rem >> 6;         // K-step 0..7
        const int l   = rem & 63;         // lane
        const int krow = kk * 32 + (l >> 4) * 8;
        const int c    = n * 16 + (l & 15);
        u32t w[4];
#pragma unroll
        for (int jj = 0; jj < 4; ++jj) {
            const int k0 = krow + 2 * jj;
            float v0 = 0.0f, v1 = 0.0f;
            if (c < NCLS) {
                v0 = Wc[k0 * NCLS + c];
                v1 = Wc[(k0 + 1) * NCLS + c];
            } else if (c < 2 * NCLS) {
                v0 = Wo[k0 * NCLS + (c - NCLS)];
                v1 = Wo[(k0 + 1) * NCLS + (c - NCLS)];
            }
            w[jj] = (u32t)f2bf_rne(v0) | ((u32t)f2bf_rne(v1) << 16);
        }
        *(uint4*)(&bB[idx * 8]) = make_uint4(w[0], w[1], w[2], w[3]);
    }
    __syncthreads();

    // ---- main: one 16-row tile per wave, K-loop of 8 x 32 ----
    const int wv = t >> 6;
    const int l  = t & 63;
    const int R0 = blockIdx.x * MTILE + wv * 16;
    const int row = R0 + (l & 15);
    const int rld = row < N_PTS ? row : N_PTS - 1;   // clamp loads, guard stores
    const float* __restrict__ arow = feats + (size_t)rld * R_FEAT + (l >> 4) * 8;

    f32x4 acc0 = {0.f, 0.f, 0.f, 0.f};
    f32x4 acc1 = {0.f, 0.f, 0.f, 0.f};
    f32x4 acc2 = {0.f, 0.f, 0.f, 0.f};

#pragma unroll
    for (int kk = 0; kk < 8; ++kk) {
        const float4 a0 = *(const float4*)(arow + kk * 32);
        const float4 a1 = *(const float4*)(arow + kk * 32 + 4);
        union { u32t u[4]; short8 s; } af;
        af.u[0] = (u32t)f2bf_rne(a0.x) | ((u32t)f2bf_rne(a0.y) << 16);
        af.u[1] = (u32t)f2bf_rne(a0.z) | ((u32t)f2bf_rne(a0.w) << 16);
        af.u[2] = (u32t)f2bf_rne(a1.x) | ((u32t)f2bf_rne(a1.y) << 16);
        af.u[3] = (u32t)f2bf_rne(a1.z) | ((u32t)f2bf_rne(a1.w) << 16);
        const short8 b0 = *(const short8*)(&bB[((0 * 8 + kk) * 64 + l) * 8]);
        const short8 b1 = *(const short8*)(&bB[((1 * 8 + kk) * 64 + l) * 8]);
        const short8 b2 = *(const short8*)(&bB[((2 * 8 + kk) * 64 + l) * 8]);
        acc0 = __builtin_amdgcn_mfma_f32_16x16x32_bf16(af.s, b0, acc0, 0, 0, 0);
        acc1 = __builtin_amdgcn_mfma_f32_16x16x32_bf16(af.s, b1, acc1, 0, 0, 0);
        acc2 = __builtin_amdgcn_mfma_f32_16x16x32_bf16(af.s, b2, acc2, 0, 0, 0);
    }

    // ---- epilogue: D col = lane&15, row = (lane>>4)*4 + j ----
    const int orow0 = R0 + (l >> 4) * 4;
    const int ocol  = l & 15;
#pragma unroll
    for (int j = 0; j < 4; ++j) {
        const int orow = orow0 + j;
        if (orow < N_PTS) {
            fwb[(size_t)orow * FW_STRIDE + ocol] = f2bf_rne(acc0[j]);          // col<16
            fwb[(size_t)orow * FW_STRIDE + 16 + ocol] = f2bf_rne(acc1[j]);     // col<32
            const int c2 = 32 + ocol;
            if (c2 < FW_STRIDE)
                fwb[(size_t)orow * FW_STRIDE + c2] = f2bf_rne(acc2[j]);        // skip pad
        }
    }
}

// ---------------- Kernel 1: masked per-segment sums of fW, atomic combine --
// grid = 8192 blocks, XCD-swizzled: bid = q*2048 + p*8 + x, s = q*8 + x.
// Mask+compact pass identical to the proven kernel. Gather: lane c (<42)
// owns channel c; 8 rows in flight per wave; bf16 load + convert + add.
// Cross-wave LDS reduce, then 42 atomicAdds/block into gacc (32-way
// contention per address).
__global__ __launch_bounds__(256) void roi_partial_kernel(
    const float* __restrict__ proposals,   // (P,6)
    const float* __restrict__ xyz,         // (N,3)
    const u16t* __restrict__ fwb,          // (N,42) bf16
    float* __restrict__ gacc)              // (P,44)
{
    const int bid = blockIdx.x;
    const int x = bid & 7;
    const int p = (bid >> 3) & (P_PROP - 1);
    const int q = bid >> 11;
    const int s = q * 8 + x;

    const int t = threadIdx.x;
    const int wave = t >> 6;
    const int lane = t & 63;

    const float cx = proposals[p * 6 + 0];
    const float cy = proposals[p * 6 + 1];
    const float cz = proposals[p * 6 + 2];
    const float hx = proposals[p * 6 + 3] * 0.5f;
    const float hy = proposals[p * 6 + 4] * 0.5f;
    const float hz = proposals[p * 6 + 5] * 0.5f;
    const float lox = cx - hx, hix = cx + hx;
    const float loy = cy - hy, hiy = cy + hy;
    const float loz = cz - hz, hiz = cz + hz;

    __shared__ int list[LIST_MAX];
    __shared__ float red[4][48];
    __shared__ int cnt;

    if (t == 0) cnt = 0;
    __syncthreads();

    const int n0 = s * SEG_LEN;
    const int n1 = n0 + SEG_LEN;

    // ---- mask + compact (single pass over the segment) ----
    for (int i = n0 + t; i < n1; i += 256) {
        const float xx = xyz[i * 3 + 0];
        const float yy = xyz[i * 3 + 1];
        const float zz = xyz[i * 3 + 2];
        const bool in = (xx >= lox) & (xx <= hix) &
                        (yy >= loy) & (yy <= hiy) &
                        (zz >= loz) & (zz <= hiz);
        const unsigned long long b = __ballot(in);
        const int prefix = __popcll(b & ((1ull << lane) - 1ull));
        const int nb = __popcll(b);
        int baseoff = 0;
        if (lane == 0 && nb) baseoff = atomicAdd(&cnt, nb);
        baseoff = __shfl(baseoff, 0, 64);
        if (in) list[baseoff + prefix] = i;
    }
    __syncthreads();

    const int m = cnt;

    // ---- gather: lane = channel, wave-strided rows, 8 rows in flight ----
    if (lane < 2 * NCLS) {
        float acc = 0.0f;
        int j = wave;
        for (; j + 28 < m; j += 32) {
            int r[8];
#pragma unroll
            for (int u = 0; u < 8; ++u) r[u] = list[j + 4 * u];
            u16t f[8];
#pragma unroll
            for (int u = 0; u < 8; ++u)
                f[u] = fwb[(size_t)r[u] * FW_STRIDE + lane];
#pragma unroll
            for (int u = 0; u < 8; ++u) acc += bf2f(f[u]);
        }
        for (; j < m; j += 4) {
            acc += bf2f(fwb[(size_t)list[j] * FW_STRIDE + lane]);
        }
        red[wave][lane] = acc;
    }
    __syncthreads();

    if (t < 2 * NCLS) {
        const float v = red[0][t] + red[1][t] + red[2][t] + red[3][t];
        atomicAdd(&gacc[p * ACC_STRIDE + t], v);
    }
    if (t == 2 * NCLS) {
        atomicAdd(&gacc[p * ACC_STRIDE + 42], (float)m);
    }
}

// ---------------- Kernel 2: logits from gacc + softmaxes + product --------
// single block, 256 threads; thread t = proposal t. Reads its 176B gacc row,
// forms logits = sums/max(cnt,1) + bias, then the proven softmax structure:
// row softmax (cls) in registers, column softmax (obj) via 8x32 LDS groups.
__global__ __launch_bounds__(256) void softmax_mul_kernel(
    const float* __restrict__ gacc,        // (P,44)
    const float* __restrict__ bc,          // (21)
    const float* __restrict__ bo,          // (21)
    float* __restrict__ out)               // (P,21)
{
    const int t = threadIdx.x;
    const int cc = t & 31;
    const int g = t >> 5;

    __shared__ float objl[P_PROP][NCLS];
    __shared__ float red[8][32];
    __shared__ float colmax[32];
    __shared__ float colsum[32];

    float4 vv[11];
    const float4* __restrict__ rowp = (const float4*)(gacc + t * ACC_STRIDE);
#pragma unroll
    for (int j = 0; j < 11; ++j) vv[j] = rowp[j];
    const float* v = (const float*)vv;

    const float cntv = fmaxf(v[42], 1.0f);
    const float rinv = 1.0f / cntv;

    float cl[NCLS], ob[NCLS];
#pragma unroll
    for (int c = 0; c < NCLS; ++c) {
        cl[c] = v[c] * rinv + bc[c];
        ob[c] = v[NCLS + c] * rinv + bo[c];
        objl[t][c] = ob[c];
    }
    __syncthreads();

    // column max (over proposals), 8 groups of 32
    float m = -INFINITY;
    if (cc < NCLS) {
        const int p0 = g * 32;
        for (int p = p0; p < p0 + 32; ++p) m = fmaxf(m, objl[p][cc]);
    }
    red[g][cc] = m;
    __syncthreads();
    if (t < NCLS) {
        float mm = red[0][t];
#pragma unroll
        for (int gg = 1; gg < 8; ++gg) mm = fmaxf(mm, red[gg][t]);
        colmax[t] = mm;
    }
    __syncthreads();

    // column sum of exp
    float sc = 0.0f;
    if (cc < NCLS) {
        const float mm = colmax[cc];
        const int p0 = g * 32;
        for (int p = p0; p < p0 + 32; ++p) sc += expf(objl[p][cc] - mm);
    }
    red[g][cc] = sc;
    __syncthreads();
    if (t < NCLS) {
        float ss = red[0][t];
#pragma unroll
        for (int gg = 1; gg < 8; ++gg) ss += red[gg][t];
        colsum[t] = ss;
    }

    // row softmax (cls) in registers meanwhile
    float rm = cl[0];
#pragma unroll
    for (int c = 1; c < NCLS; ++c) rm = fmaxf(rm, cl[c]);
    float e[NCLS];
    float rs = 0.0f;
#pragma unroll
    for (int c = 0; c < NCLS; ++c) { e[c] = expf(cl[c] - rm); rs += e[c]; }
    const float inv = 1.0f / rs;

    __syncthreads();

#pragma unroll
    for (int c = 0; c < NCLS; ++c) {
        const float cp = e[c] * inv;
        const float op = expf(ob[c] - colmax[c]) / colsum[c];
        out[t * NCLS + c] = cp * op;
    }
}

// ---------------- launch ----------------------------------------------------
extern "C" void kernel_launch(void* const* d_in, const int* in_sizes, int n_in,
                              void* d_out, int out_size, void* d_ws, size_t ws_size,
                              hipStream_t stream) {
    const float* proposals = (const float*)d_in[0];  // (256,6)
    const float* xyz       = (const float*)d_in[1];  // (100000,3)
    const float* feats     = (const float*)d_in[2];  // (100000,256)
    const float* Wc        = (const float*)d_in[3];  // (256,21)
    const float* bc        = (const float*)d_in[4];  // (21)
    const float* Wo        = (const float*)d_in[5];  // (256,21)
    const float* bo        = (const float*)d_in[6];  // (21)
    float* out = (float*)d_out;                      // (256,21)

    char* ws = (char*)d_ws;
    u16t* fwb   = (u16t*)(ws);                       // 100000*42*2 = 8,400,000 B
    float* gacc = (float*)(ws + 8400000);            // 256*44*4    = 45,056 B

    featw_kernel<<<FEATW_BLOCKS, 256, 0, stream>>>(feats, Wc, Wo, fwb, gacc);
    roi_partial_kernel<<<P_PROP * NSEG, 256, 0, stream>>>(proposals, xyz, fwb, gacc);
    softmax_mul_kernel<<<1, 256, 0, stream>>>(gacc, bc, bo, out);
}